// Round 7
// baseline (297.668 us; speedup 1.0000x reference)
//
#include <hip/hip_runtime.h>
#include <hip/hip_fp16.h>

// out[M,N] = fp16( a[M,K] @ (w_q[K,N] * scale[K/G,N]) ), G=128, all dims 4096.
// Harness dtype contract: fp16 tensors passed/returned as FLOAT32.
// Round 7: break the 1-block/CU barrier lockstep (R2..R6 showed no intra-
// block schedule beats burst-reads; LDS-drain and MFMA serialize at ~2300
// cyc/phase). New geometry: 128x256 tile, 256 threads (4 waves), LDS ring-3
// (72 KB) -> TWO independent blocks per CU. Same per-wave work and counted
// vmcnt (stage distance 2, steady vmcnt(6), never 0); cross-block async
// fills the MFMA pipe while the other block drains LDS (m114 overlap).
#define MDIM 4096
#define NDIM 4096
#define KDIM 4096
#define NT 256
#define WBLK 4096

typedef _Float16 f16x8 __attribute__((ext_vector_type(8)));
typedef float f32x4 __attribute__((ext_vector_type(4)));
typedef unsigned int u32;
typedef unsigned short u16;

__device__ inline __half2 as_half2(u32 u) { return __builtin_bit_cast(__half2, u); }
__device__ inline u32 as_u32(__half2 h) { return __builtin_bit_cast(u32, h); }
// __builtin_amdgcn_cvt_pkrtz returns __fp16 ext_vector(2); bit-cast directly.
__device__ inline u32 pkrtz(float a, float b) {
  return __builtin_bit_cast(u32, __builtin_amdgcn_cvt_pkrtz(a, b));
}

// async global -> LDS, 16 B/lane. LDS dst must be wave-uniform base + lane*16.
__device__ inline void load16_to_lds(const void* g, void* l) {
  __builtin_amdgcn_global_load_lds(
      (__attribute__((address_space(1))) const u32*)g,
      (__attribute__((address_space(3))) u32*)l,
      16, 0, 0);
}

template <int VM>
__device__ __forceinline__ void wait_vmcnt() {
  if constexpr (VM == 6)
    asm volatile("s_waitcnt vmcnt(6)" ::: "memory");
  else
    asm volatile("s_waitcnt vmcnt(0)" ::: "memory");
}

// ---- fused prepass: blocks [0,4096) dequant+transpose W, rest copy A ----
__global__ __launch_bounds__(NT) void prep(const float* __restrict__ A,
                                           _Float16* __restrict__ A16,
                                           const int* __restrict__ Wq,
                                           const float* __restrict__ Sc,
                                           _Float16* __restrict__ Wt) {
  // u32 staging [n][k-pair], stride 33 dwords: write bank (n+kp)%32 (2-way),
  // read bank (n+k2c+j)%32 (2-way). 8.25 KB -> high occupancy.
  __shared__ u32 Lt[64 * 33];
  const int tid = threadIdx.x;

  if (blockIdx.x >= WBLK) {
    // ---- A fp32 -> fp16 (exact: values are fp16-representable) ----
    const size_t b = blockIdx.x - WBLK;
    const size_t base = (b * NT + tid) * 8;
    const float4 f0 = *(const float4*)(A + base);
    const float4 f1 = *(const float4*)(A + base + 4);
    u32 pk[4];
    pk[0] = pkrtz(f0.x, f0.y);
    pk[1] = pkrtz(f0.z, f0.w);
    pk[2] = pkrtz(f1.x, f1.y);
    pk[3] = pkrtz(f1.z, f1.w);
    *(uint4*)(A16 + base) = *(const uint4*)pk;
    return;
  }

  // ---- W: dequant Wq [K][N] + transpose -> Wt f16 [N][K], 64x64 tile ----
  const int n0 = (blockIdx.x & 63) * 64;
  const int k0 = (blockIdx.x >> 6) * 64;
  const int g = k0 >> 7;  // 64-tile lies within one 128-group

  // phase 1: coalesced read of two adjacent k-rows, dequant to packed k-pair
#pragma unroll
  for (int r = 0; r < 2; ++r) {
    const int idx = r * 256 + tid;
    const int kp = idx >> 4;          // k-pair index 0..31
    const int col4 = (idx & 15) * 4;  // n within tile, 4 at a time
    const int4 va = *(const int4*)(Wq + (size_t)(k0 + 2 * kp) * NDIM + n0 + col4);
    const int4 vb = *(const int4*)(Wq + (size_t)(k0 + 2 * kp + 1) * NDIM + n0 + col4);
    const float4 s = *(const float4*)(Sc + (size_t)g * NDIM + n0 + col4);
    const float sf[4] = {s.x, s.y, s.z, s.w};
    const int av[4] = {va.x, va.y, va.z, va.w};
    const int bv[4] = {vb.x, vb.y, vb.z, vb.w};
#pragma unroll
    for (int i = 0; i < 4; ++i) {
      // fp16 bits of (1024+v): 0x6400|v; hfma gives single-rounded v*s.
      const __half hs = __float2half(sf[i]);
      const __half2 s2 = __half2half2(hs);
      const __half2 nb = __half2half2(__hmul(hs, __float2half(-1024.0f)));
      const u32 u = (u32)av[i] | ((u32)bv[i] << 16) | 0x64006400u;
      // u32 holds (w[2kp]*s, w[2kp+1]*s) = the contiguous k-pair for Wt[n].
      Lt[(size_t)(col4 + i) * 33 + kp] = as_u32(__hfma2(as_half2(u), s2, nb));
    }
  }
  __syncthreads();

  // phase 2: gather 4 k-pair dwords per thread, coalesced 16B writes to Wt
#pragma unroll
  for (int r = 0; r < 2; ++r) {
    const int idx = r * 256 + tid;
    const int n = idx >> 3;          // 0..63
    const int k2c = (idx & 7) * 4;   // dword column 0..28 (= k/2)
    u32 v[4];
#pragma unroll
    for (int j = 0; j < 4; ++j) v[j] = Lt[(size_t)n * 33 + k2c + j];
    *(uint4*)(Wt + (size_t)(n0 + n) * KDIM + k0 + k2c * 2) = *(const uint4*)v;
  }
}

// ------------- 128x256 tile, 4-wave, ring-3, 2 blocks/CU GEMM -------------
// LDS ring of 3 slots per operand: A slot [128][32] f16 (8 KB), B slot
// [256][32] f16 (16 KB) -> 72 KB/block, 2 blocks/CU resident.
// Phase p: wait vmcnt(6) -> barrier -> 12 frag ds_read_b128 -> stage(p+2)
//   (A 2 + B 4 gloads/thread = 6 vmcnt events) -> lgkm0 -> 32 MFMA.
// Steady state: stages p+1,p+2 in flight (6 newer than the needed stage p).
// Slot p%3 safety: stage(p+2) targets slot (p+2)%3 = (p-1)%3, whose readers
// (phase p-1) completed their ds_reads (lgkm0) before entering the barrier
// at the top of phase p.
// Swizzle: physical chunk = logical ^ ((row>>1)&3), on the per-lane GLOBAL
// source (LDS dst linear for global_load_lds) and on frag reads (0 confl).
__global__ __launch_bounds__(NT, 2) void gemm_f16(const _Float16* __restrict__ A16,
                                                  const _Float16* __restrict__ Wt,
                                                  float* __restrict__ C) {
  __shared__ __align__(16) _Float16 As[3 * 128 * 32];  // 24 KB
  __shared__ __align__(16) _Float16 Bs[3 * 256 * 32];  // 48 KB

  const int tid = threadIdx.x;
  const int bx = blockIdx.x & 15;  // n-block (256 wide)
  const int by = blockIdx.x >> 4;  // m-block (128 tall)
  const int m_base = by * 128;
  const int n_base = bx * 256;

  const int lane = tid & 63;
  const int l15 = lane & 15;
  const int quad = lane >> 4;
  const int nq = tid >> 6;             // wave 0..3 : 64-col band
  const int gq = (l15 >> 1) & 3;       // row-swizzle term (row ≡ l15 mod 16)
  const int pchunk = quad ^ gq;        // physical 16B chunk for frag reads

  f32x4 acc[8][4];
#pragma unroll
  for (int i = 0; i < 8; ++i)
#pragma unroll
    for (int j = 0; j < 4; ++j) acc[i][j] = (f32x4)0.0f;

  // stage k-half piece q into slot sq: A 2 + B 4 global_load_lds per thread.
  auto stage = [&](int q, int sq) {
    const size_t kof = (size_t)q * 32;
#pragma unroll
    for (int L = 0; L < 2; ++L) {
      const int cc = L * 256 + tid;        // 0..511 : (row, phys chunk)
      const int row = cc >> 2;             // 0..127
      const int lch = (cc & 3) ^ ((row >> 1) & 3);  // logical chunk at phys
      load16_to_lds(A16 + (size_t)(m_base + row) * KDIM + kof + lch * 8,
                    (char*)As + (size_t)sq * 8192 + (size_t)cc * 16);
    }
#pragma unroll
    for (int L = 0; L < 4; ++L) {
      const int cc = L * 256 + tid;        // 0..1023
      const int row = cc >> 2;             // 0..255
      const int lch = (cc & 3) ^ ((row >> 1) & 3);
      load16_to_lds(Wt + (size_t)(n_base + row) * KDIM + kof + lch * 8,
                    (char*)Bs + (size_t)sq * 16384 + (size_t)cc * 16);
    }
  };

  // caller performs the top-of-phase wait_vmcnt BEFORE calling.
  auto phase_body = [&](int p, int s, bool dostage) {
    __builtin_amdgcn_s_barrier();
    asm volatile("" ::: "memory");  // no LDS access hoists above the barrier
    const _Float16* Ab = (const _Float16*)((const char*)As + (size_t)s * 8192);
    const _Float16* Bb = (const _Float16*)((const char*)Bs + (size_t)s * 16384);
    f16x8 af[8], bf[4];
#pragma unroll
    for (int i = 0; i < 8; ++i) {
      const int row = i * 16 + l15;
      af[i] = *(const f16x8*)(Ab + (size_t)row * 32 + pchunk * 8);
    }
#pragma unroll
    for (int j = 0; j < 4; ++j) {
      const int row = nq * 64 + j * 16 + l15;
      bf[j] = *(const f16x8*)(Bb + (size_t)row * 32 + pchunk * 8);
    }
    if (dostage) {
      int s2 = s + 2;
      if (s2 >= 3) s2 -= 3;
      stage(p + 2, s2);  // VMEM issue overlaps the MFMA block
    }
    asm volatile("s_waitcnt lgkmcnt(0)" ::: "memory");
    __builtin_amdgcn_sched_barrier(0);  // keep MFMAs below the wait (rule 18)
    __builtin_amdgcn_s_setprio(1);
#pragma unroll
    for (int i = 0; i < 8; ++i)
#pragma unroll
      for (int j = 0; j < 4; ++j)
        acc[i][j] = __builtin_amdgcn_mfma_f32_16x16x32_f16(af[i], bf[j],
                                                           acc[i][j], 0, 0, 0);
    __builtin_amdgcn_s_setprio(0);
  };

  // prologue: pieces 0,1 in flight (12 vmcnt events)
  stage(0, 0);
  stage(1, 1);

  // 128 phases = 64 K-tiles x 2 k-halves. Entry wait vmcnt(6): stage(p+1)
  // (6 events, issued at p-1) outstanding; stage(p) guaranteed landed.
  int s = 0;
  for (int p = 0; p < 126; ++p) {
    wait_vmcnt<6>();
    phase_body(p, s, true);  // stages pieces 2..127
    if (++s == 3) s = 0;
  }
  wait_vmcnt<6>();
  phase_body(126, s, false);
  if (++s == 3) s = 0;
  wait_vmcnt<0>();
  phase_body(127, s, false);

  // epilogue: C/D layout col=lane&15, row=quad*4+reg; fp16-round, store f32
#pragma unroll
  for (int i = 0; i < 8; ++i) {
#pragma unroll
    for (int j = 0; j < 4; ++j) {
      const int col = n_base + nq * 64 + j * 16 + l15;
#pragma unroll
      for (int r = 0; r < 4; ++r) {
        const int row = m_base + i * 16 + quad * 4 + r;
        C[(size_t)row * NDIM + col] = __half2float(__float2half(acc[i][j][r]));
      }
    }
  }
}

// ---------------- fallback: fused single-kernel (round-3, 331 us) --------
#define STR 72
__global__ __launch_bounds__(NT) void qgemm_fused(
    const float* __restrict__ A, const int* __restrict__ Wq,
    const float* __restrict__ Sc, float* __restrict__ C) {
  __shared__ __align__(16) _Float16 As[128 * STR];
  __shared__ __align__(16) _Float16 Bs[128 * STR];
  const int tid = threadIdx.x;
  const int bx = blockIdx.x & 31, by = blockIdx.x >> 5;
  const int m_base = by * 128, n_base = bx * 128;
  const int wave = tid >> 6, lane = tid & 63;
  const int l15 = lane & 15, quad = lane >> 4;
  const int wm = (wave & 1) * 64, wn = (wave >> 1) * 64;
  const int bn_local = tid & 127, bk_half = (tid >> 7) * 8;
  const int gn = n_base + bn_local;
  f32x4 acc[4][4];
#pragma unroll
  for (int i = 0; i < 4; ++i)
#pragma unroll
    for (int j = 0; j < 4; ++j) acc[i][j] = (f32x4)0.0f;
  for (int kt = 0; kt < KDIM / 64; ++kt) {
    const int k0 = kt * 64;
    __syncthreads();
#pragma unroll
    for (int i = 0; i < 8; ++i) {
      const int c = i * 256 + tid;
      const int row = c >> 4, col4 = (c & 15) * 4;
      const float4 f = *(const float4*)(A + (size_t)(m_base + row) * KDIM + k0 + col4);
      u32 pk[2];
      pk[0] = pkrtz(f.x, f.y);
      pk[1] = pkrtz(f.z, f.w);
      *(uint2*)&As[(size_t)row * STR + col4] = *(const uint2*)pk;
    }
    {
      const __half hs = __float2half(Sc[(size_t)(k0 >> 7) * NDIM + gn]);
      const __half2 s2 = __half2half2(hs);
      const __half2 nb2 = __half2half2(__hmul(hs, __float2half(-1024.0f)));
#pragma unroll
      for (int it = 0; it < 4; ++it) {
        const int k = bk_half + it * 16;
        u32 v[8];
#pragma unroll
        for (int j = 0; j < 8; ++j)
          v[j] = (u32)Wq[(size_t)(k0 + k + j) * NDIM + gn];
        u32 pk[4];
#pragma unroll
        for (int p = 0; p < 4; ++p) {
          u32 u = v[2 * p] | (v[2 * p + 1] << 16) | 0x64006400u;
          pk[p] = as_u32(__hfma2(as_half2(u), s2, nb2));
        }
        *(uint4*)&Bs[(size_t)bn_local * STR + k] = *(const uint4*)pk;
      }
    }
    __syncthreads();
#pragma unroll
    for (int ks = 0; ks < 64; ks += 32) {
      f16x8 af[4], bf[4];
#pragma unroll
      for (int i = 0; i < 4; ++i)
        af[i] = *(const f16x8*)&As[(size_t)(wm + i * 16 + l15) * STR + ks + quad * 8];
#pragma unroll
      for (int j = 0; j < 4; ++j)
        bf[j] = *(const f16x8*)&Bs[(size_t)(wn + j * 16 + l15) * STR + ks + quad * 8];
#pragma unroll
      for (int i = 0; i < 4; ++i)
#pragma unroll
        for (int j = 0; j < 4; ++j)
          acc[i][j] = __builtin_amdgcn_mfma_f32_16x16x32_f16(af[i], bf[j],
                                                             acc[i][j], 0, 0, 0);
    }
  }
#pragma unroll
  for (int i = 0; i < 4; ++i)
#pragma unroll
    for (int j = 0; j < 4; ++j) {
      const int col = n_base + wn + j * 16 + l15;
#pragma unroll
      for (int r = 0; r < 4; ++r) {
        const int row = m_base + wm + i * 16 + quad * 4 + r;
        C[(size_t)row * NDIM + col] = __half2float(__float2half(acc[i][j][r]));
      }
    }
}

extern "C" void kernel_launch(void* const* d_in, const int* in_sizes, int n_in,
                              void* d_out, int out_size, void* d_ws, size_t ws_size,
                              hipStream_t stream) {
  const float* a = (const float*)d_in[0];
  const int* wq = (const int*)d_in[1];
  const float* sc = (const float*)d_in[2];
  float* out = (float*)d_out;

  const size_t a16_bytes = (size_t)MDIM * KDIM * 2;  // 32 MiB
  const size_t wt_bytes = (size_t)NDIM * KDIM * 2;   // 32 MiB

  if (ws_size >= a16_bytes + wt_bytes) {
    _Float16* a16 = (_Float16*)d_ws;
    _Float16* wt = (_Float16*)((char*)d_ws + a16_bytes);
    const int a_blocks = (MDIM * KDIM) / (NT * 8);  // 8192
    prep<<<WBLK + a_blocks, NT, 0, stream>>>(a, a16, wq, sc, wt);
    gemm_f16<<<(MDIM / 128) * (NDIM / 256), NT, 0, stream>>>(a16, wt, out);
  } else {
    qgemm_fused<<<(MDIM / 128) * (NDIM / 128), NT, 0, stream>>>(a, wq, sc, out);
  }
}